// Round 1
// baseline (9935.087 us; speedup 1.0000x reference)
//
#include <hip/hip_runtime.h>
#include <math.h>

#define SD 10

__device__ __forceinline__ float tanh_fast(float x) {
    // tanh(x) = 1 - 2/(1+exp(2x)); saturates correctly at +/-inf
    float e = __expf(2.0f * x);
    float r = __builtin_amdgcn_rcpf(1.0f + e);
    return 1.0f - 2.0f * r;
}

__device__ __forceinline__ float softplus_f(float x) {
    // stable: max(x,0) + log1p(exp(-|x|))
    return fmaxf(x, 0.0f) + log1pf(expf(-fabsf(x)));
}

template <bool FIRST>
__global__ __launch_bounds__(256) void edge_kernel(
    const float* __restrict__ coords,   // (N,3)
    const float* __restrict__ elen,     // (E,1)
    const float* __restrict__ evec,     // (E,3)
    const float* __restrict__ Wm,       // (14,10) row-major
    const float* __restrict__ bm,       // (10,)
    const int* __restrict__ nfrom,      // (E,)
    const int* __restrict__ nto,        // (E,)
    const float* __restrict__ state_prev,  // (N,10)
    float* __restrict__ state_next,        // (N,10), pre-initialized to state_prev (or 0)
    int E)
{
    int e = blockIdx.x * blockDim.x + threadIdx.x;
    if (e >= E) return;

    int nf = nfrom[e];
    int nt = nto[e];

    float cf0 = coords[nf * 3 + 0], cf1 = coords[nf * 3 + 1], cf2 = coords[nf * 3 + 2];
    float ct0 = coords[nt * 3 + 0], ct1 = coords[nt * 3 + 1], ct2 = coords[nt * 3 + 2];
    float ev0 = evec[e * 3 + 0], ev1 = evec[e * 3 + 1], ev2 = evec[e * 3 + 2];

    float g0 = elen[e];
    float g1 = fabsf(cf0) + fabsf(cf1) + fabsf(cf2);
    float g2 = cf0 * ct0 + cf1 * ct1 + cf2 * ct2;
    float g3 = cf0 * ev0 + cf1 * ev1 + cf2 * ev2;

    float acc[SD];
#pragma unroll
    for (int j = 0; j < SD; j++) {
        acc[j] = bm[j]
               + g0 * Wm[10 * SD + j]
               + g1 * Wm[11 * SD + j]
               + g2 * Wm[12 * SD + j]
               + g3 * Wm[13 * SD + j];
    }

    if (!FIRST) {
        // state row: 40B, 8B-aligned -> 5x dwordx2
        const float2* sp = (const float2*)(state_prev + (size_t)nf * SD);
        float s[SD];
#pragma unroll
        for (int h = 0; h < 5; h++) {
            float2 v = sp[h];
            s[2 * h] = v.x;
            s[2 * h + 1] = v.y;
        }
#pragma unroll
        for (int k = 0; k < SD; k++) {
#pragma unroll
            for (int j = 0; j < SD; j++) acc[j] += s[k] * Wm[k * SD + j];
        }
    }

    float* dst = state_next + (size_t)nt * SD;
#pragma unroll
    for (int j = 0; j < SD; j++) atomicAdd(dst + j, tanh_fast(acc[j]));
}

__global__ __launch_bounds__(256) void graph_reduce_kernel(
    const float* __restrict__ state,   // (N,10)
    const int* __restrict__ gidx,      // (N,)
    float* __restrict__ gstate,        // (G,10), zero-initialized
    int N)
{
    int n = blockIdx.x * blockDim.x + threadIdx.x;
    if (n >= N) return;
    int g = gidx[n];
    const float2* sp = (const float2*)(state + (size_t)n * SD);
    float* dst = gstate + (size_t)g * SD;
#pragma unroll
    for (int h = 0; h < 5; h++) {
        float2 v = sp[h];
        atomicAdd(dst + 2 * h, v.x);
        atomicAdd(dst + 2 * h + 1, v.y);
    }
}

__global__ __launch_bounds__(256) void out_kernel(
    const float* __restrict__ gstate,  // (G,10)
    const float* __restrict__ Wo,      // (10,4) row-major
    const float* __restrict__ bo,      // (4,)
    float* __restrict__ out,           // (G,4)
    int G)
{
    int g = blockIdx.x * blockDim.x + threadIdx.x;
    if (g >= G) return;
    float s[SD];
#pragma unroll
    for (int k = 0; k < SD; k++) s[k] = gstate[(size_t)g * SD + k];
    float ev[4];
#pragma unroll
    for (int c = 0; c < 4; c++) {
        float a = bo[c];
#pragma unroll
        for (int k = 0; k < SD; k++) a += s[k] * Wo[k * 4 + c];
        ev[c] = a;
    }
    out[g * 4 + 0] = ev[0];
    out[g * 4 + 1] = softplus_f(ev[1]);
    out[g * 4 + 2] = softplus_f(ev[2]) + 1.0f;
    out[g * 4 + 3] = softplus_f(ev[3]);
}

extern "C" void kernel_launch(void* const* d_in, const int* in_sizes, int n_in,
                              void* d_out, int out_size, void* d_ws, size_t ws_size,
                              hipStream_t stream) {
    const float* coords = (const float*)d_in[0];   // N*3
    const float* elen   = (const float*)d_in[1];   // E
    const float* evec   = (const float*)d_in[2];   // E*3
    const float* Wm     = (const float*)d_in[3];   // 140
    const float* bm     = (const float*)d_in[4];   // 10
    const float* Wo     = (const float*)d_in[5];   // 40
    const float* bo     = (const float*)d_in[6];   // 4
    const int* nfrom    = (const int*)d_in[7];     // E
    const int* nto      = (const int*)d_in[8];     // E
    const int* gidx     = (const int*)d_in[9];     // N

    const int E = in_sizes[1];
    const int N = in_sizes[9];
    const int G = out_size / 4;

    const size_t state_bytes = (size_t)N * SD * sizeof(float);  // 8,000,000 B (256-aligned)
    char* w = (char*)d_ws;
    float* stateA = (float*)w;
    float* stateB = (float*)(w + state_bytes);
    float* gstate = (float*)(w + 2 * state_bytes);

    const int BLK = 256;
    const int eg = (E + BLK - 1) / BLK;
    const int ng = (N + BLK - 1) / BLK;
    const int gg = (G + BLK - 1) / BLK;

    // Round 1: state=0 -> stateA accumulates tanh(geo path) directly.
    hipMemsetAsync(stateA, 0, state_bytes, stream);
    hipMemsetAsync(gstate, 0, (size_t)G * SD * sizeof(float), stream);
    edge_kernel<true><<<eg, BLK, 0, stream>>>(coords, elen, evec, Wm, bm, nfrom, nto,
                                              stateA, stateA, E);
    // Round 2: read stateA, accumulate into stateB (= copy of stateA).
    hipMemcpyAsync(stateB, stateA, state_bytes, hipMemcpyDeviceToDevice, stream);
    edge_kernel<false><<<eg, BLK, 0, stream>>>(coords, elen, evec, Wm, bm, nfrom, nto,
                                               stateA, stateB, E);
    // Round 3: read stateB, accumulate into stateA (= copy of stateB).
    hipMemcpyAsync(stateA, stateB, state_bytes, hipMemcpyDeviceToDevice, stream);
    edge_kernel<false><<<eg, BLK, 0, stream>>>(coords, elen, evec, Wm, bm, nfrom, nto,
                                               stateB, stateA, E);

    graph_reduce_kernel<<<ng, BLK, 0, stream>>>(stateA, gidx, gstate, N);
    out_kernel<<<gg, BLK, 0, stream>>>(gstate, Wo, bo, (float*)d_out, G);
}

// Round 2
// 1843.372 us; speedup vs baseline: 5.3896x; 5.3896x over previous
//
#include <hip/hip_runtime.h>
#include <math.h>

#define SD 10

__device__ __forceinline__ float tanh_fast(float x) {
    float e = __expf(2.0f * x);
    float r = __builtin_amdgcn_rcpf(1.0f + e);
    return 1.0f - 2.0f * r;
}

__device__ __forceinline__ float softplus_f(float x) {
    return fmaxf(x, 0.0f) + log1pf(expf(-fabsf(x)));
}

// ============================ CSR build ============================

__global__ __launch_bounds__(256) void hist_kernel(
    const int* __restrict__ nto, unsigned* __restrict__ cnt, int E)
{
    int e = blockIdx.x * blockDim.x + threadIdx.x;
    if (e >= E) return;
    atomicAdd(&cnt[nto[e]], 1u);
}

// Exclusive scan, level 1: 1024 items per 256-thread block.
__global__ __launch_bounds__(256) void scan1_kernel(
    const unsigned* __restrict__ cnt, unsigned* __restrict__ off,
    unsigned* __restrict__ bsum, int N)
{
    __shared__ unsigned lds[256];
    int t = threadIdx.x, b = blockIdx.x;
    int base = b * 1024 + t * 4;
    unsigned v[4], s = 0;
#pragma unroll
    for (int k = 0; k < 4; k++) {
        v[k] = (base + k < N) ? cnt[base + k] : 0u;
        s += v[k];
    }
    lds[t] = s;
    __syncthreads();
    for (int d = 1; d < 256; d <<= 1) {
        unsigned x = (t >= d) ? lds[t - d] : 0u;
        __syncthreads();
        lds[t] += x;
        __syncthreads();
    }
    unsigned excl = (t > 0) ? lds[t - 1] : 0u;
    if (t == 255) bsum[b] = lds[255];
    unsigned run = excl;
#pragma unroll
    for (int k = 0; k < 4; k++) {
        if (base + k < N) off[base + k] = run;
        run += v[k];
    }
}

// Level 2: exclusive scan of block sums (nb <= 256; N <= 262144).
__global__ __launch_bounds__(256) void scan2_kernel(unsigned* __restrict__ bsum, int nb)
{
    __shared__ unsigned lds[256];
    int t = threadIdx.x;
    unsigned v = (t < nb) ? bsum[t] : 0u;
    lds[t] = v;
    __syncthreads();
    for (int d = 1; d < 256; d <<= 1) {
        unsigned x = (t >= d) ? lds[t - d] : 0u;
        __syncthreads();
        lds[t] += x;
        __syncthreads();
    }
    unsigned excl = (t > 0) ? lds[t - 1] : 0u;
    if (t < nb) bsum[t] = excl;
}

// Level 3: add block bases; produce cur copy; set off[N]=E.
__global__ __launch_bounds__(256) void scan3_kernel(
    unsigned* __restrict__ off, unsigned* __restrict__ cur,
    const unsigned* __restrict__ bsum, int N, int E)
{
    int i = blockIdx.x * blockDim.x + threadIdx.x;
    if (i == 0) off[N] = (unsigned)E;
    if (i >= N) return;
    unsigned o = off[i] + bsum[i >> 10];
    off[i] = o;
    cur[i] = o;
}

// Scatter edges into destination-sorted order; compute round-invariant geo.
__global__ __launch_bounds__(256) void scatter_kernel(
    const float* __restrict__ coords,
    const float* __restrict__ elen,
    const float* __restrict__ evec,
    const int* __restrict__ nfrom,
    const int* __restrict__ nto,
    unsigned* __restrict__ cur,
    int* __restrict__ nfrom_s,
    float4* __restrict__ geo_s,
    int E)
{
    int e = blockIdx.x * blockDim.x + threadIdx.x;
    if (e >= E) return;
    int nf = nfrom[e];
    int nt = nto[e];
    unsigned pos = atomicAdd(&cur[nt], 1u);

    float cf0 = coords[nf * 3 + 0], cf1 = coords[nf * 3 + 1], cf2 = coords[nf * 3 + 2];
    float ct0 = coords[nt * 3 + 0], ct1 = coords[nt * 3 + 1], ct2 = coords[nt * 3 + 2];
    float ev0 = evec[e * 3 + 0], ev1 = evec[e * 3 + 1], ev2 = evec[e * 3 + 2];

    float4 g;
    g.x = elen[e];
    g.y = fabsf(cf0) + fabsf(cf1) + fabsf(cf2);
    g.z = cf0 * ct0 + cf1 * ct1 + cf2 * ct2;
    g.w = cf0 * ev0 + cf1 * ev1 + cf2 * ev2;

    nfrom_s[pos] = nf;
    geo_s[pos] = g;
}

// ============================ rounds (gather, no atomics) ============================

template <bool FIRST>
__global__ __launch_bounds__(256) void round_kernel(
    const unsigned* __restrict__ off,
    const int* __restrict__ nfrom_s,
    const float4* __restrict__ geo_s,
    const float* __restrict__ Wm,     // (14,10)
    const float* __restrict__ bm,     // (10,)
    const float* __restrict__ state_prev,
    float* __restrict__ state_next,
    int N)
{
    int n = blockIdx.x * blockDim.x + threadIdx.x;
    if (n >= N) return;
    unsigned beg = off[n], end = off[n + 1];

    float acc[SD];
    if (FIRST) {
#pragma unroll
        for (int j = 0; j < SD; j++) acc[j] = 0.0f;
    } else {
        const float2* sp = (const float2*)(state_prev + (size_t)n * SD);
#pragma unroll
        for (int h = 0; h < 5; h++) {
            float2 v = sp[h];
            acc[2 * h] = v.x;
            acc[2 * h + 1] = v.y;
        }
    }

    for (unsigned i = beg; i < end; i++) {
        float4 g = geo_s[i];
        float t[SD];
#pragma unroll
        for (int j = 0; j < SD; j++) {
            t[j] = bm[j]
                 + g.x * Wm[10 * SD + j]
                 + g.y * Wm[11 * SD + j]
                 + g.z * Wm[12 * SD + j]
                 + g.w * Wm[13 * SD + j];
        }
        if (!FIRST) {
            int nf = nfrom_s[i];
            const float2* sp = (const float2*)(state_prev + (size_t)nf * SD);
            float s[SD];
#pragma unroll
            for (int h = 0; h < 5; h++) {
                float2 v = sp[h];
                s[2 * h] = v.x;
                s[2 * h + 1] = v.y;
            }
#pragma unroll
            for (int k = 0; k < SD; k++) {
#pragma unroll
                for (int j = 0; j < SD; j++) t[j] += s[k] * Wm[k * SD + j];
            }
        }
#pragma unroll
        for (int j = 0; j < SD; j++) acc[j] += tanh_fast(t[j]);
    }

    float2* dp = (float2*)(state_next + (size_t)n * SD);
#pragma unroll
    for (int h = 0; h < 5; h++) {
        float2 v;
        v.x = acc[2 * h];
        v.y = acc[2 * h + 1];
        dp[h] = v;
    }
}

// ============================ graph phase ============================

// goff[g] = first node index with gidx >= g; goff[G] = N. gidx is sorted.
__global__ __launch_bounds__(256) void goff_kernel(
    const int* __restrict__ gidx, unsigned* __restrict__ goff, int N, int G)
{
    int n = blockIdx.x * blockDim.x + threadIdx.x;
    if (n >= N) return;
    int g = gidx[n];
    if (n == 0) {
        for (int q = 0; q <= g; q++) goff[q] = 0;
    } else {
        int gp = gidx[n - 1];
        for (int q = gp + 1; q <= g; q++) goff[q] = (unsigned)n;
    }
    if (n == N - 1) {
        for (int q = g + 1; q <= G; q++) goff[q] = (unsigned)N;
    }
}

// one thread per (g, j): 10 consecutive threads share g -> coalesced 40B reads
__global__ __launch_bounds__(256) void gsum_kernel(
    const float* __restrict__ state,
    const unsigned* __restrict__ goff,
    float* __restrict__ gstate,
    int G)
{
    int tid = blockIdx.x * blockDim.x + threadIdx.x;
    if (tid >= G * SD) return;
    int g = tid / SD;
    int j = tid % SD;
    unsigned beg = goff[g], end = goff[g + 1];
    float a = 0.0f;
    for (unsigned n = beg; n < end; n++) a += state[(size_t)n * SD + j];
    gstate[(size_t)g * SD + j] = a;
}

__global__ __launch_bounds__(256) void out_kernel(
    const float* __restrict__ gstate,
    const float* __restrict__ Wo,
    const float* __restrict__ bo,
    float* __restrict__ out,
    int G)
{
    int g = blockIdx.x * blockDim.x + threadIdx.x;
    if (g >= G) return;
    float s[SD];
#pragma unroll
    for (int k = 0; k < SD; k++) s[k] = gstate[(size_t)g * SD + k];
    float ev[4];
#pragma unroll
    for (int c = 0; c < 4; c++) {
        float a = bo[c];
#pragma unroll
        for (int k = 0; k < SD; k++) a += s[k] * Wo[k * 4 + c];
        ev[c] = a;
    }
    out[g * 4 + 0] = ev[0];
    out[g * 4 + 1] = softplus_f(ev[1]);
    out[g * 4 + 2] = softplus_f(ev[2]) + 1.0f;
    out[g * 4 + 3] = softplus_f(ev[3]);
}

// ============================ fallback (R0 atomic path) ============================

template <bool FIRST>
__global__ __launch_bounds__(256) void edge_kernel_fb(
    const float* __restrict__ coords, const float* __restrict__ elen,
    const float* __restrict__ evec, const float* __restrict__ Wm,
    const float* __restrict__ bm, const int* __restrict__ nfrom,
    const int* __restrict__ nto, const float* __restrict__ state_prev,
    float* __restrict__ state_next, int E)
{
    int e = blockIdx.x * blockDim.x + threadIdx.x;
    if (e >= E) return;
    int nf = nfrom[e];
    int nt = nto[e];
    float cf0 = coords[nf * 3 + 0], cf1 = coords[nf * 3 + 1], cf2 = coords[nf * 3 + 2];
    float ct0 = coords[nt * 3 + 0], ct1 = coords[nt * 3 + 1], ct2 = coords[nt * 3 + 2];
    float ev0 = evec[e * 3 + 0], ev1 = evec[e * 3 + 1], ev2 = evec[e * 3 + 2];
    float g0 = elen[e];
    float g1 = fabsf(cf0) + fabsf(cf1) + fabsf(cf2);
    float g2 = cf0 * ct0 + cf1 * ct1 + cf2 * ct2;
    float g3 = cf0 * ev0 + cf1 * ev1 + cf2 * ev2;
    float acc[SD];
#pragma unroll
    for (int j = 0; j < SD; j++) {
        acc[j] = bm[j] + g0 * Wm[10 * SD + j] + g1 * Wm[11 * SD + j]
               + g2 * Wm[12 * SD + j] + g3 * Wm[13 * SD + j];
    }
    if (!FIRST) {
        const float2* sp = (const float2*)(state_prev + (size_t)nf * SD);
        float s[SD];
#pragma unroll
        for (int h = 0; h < 5; h++) {
            float2 v = sp[h];
            s[2 * h] = v.x;
            s[2 * h + 1] = v.y;
        }
#pragma unroll
        for (int k = 0; k < SD; k++) {
#pragma unroll
            for (int j = 0; j < SD; j++) acc[j] += s[k] * Wm[k * SD + j];
        }
    }
    float* dst = state_next + (size_t)nt * SD;
#pragma unroll
    for (int j = 0; j < SD; j++) atomicAdd(dst + j, tanh_fast(acc[j]));
}

__global__ __launch_bounds__(256) void graph_reduce_fb(
    const float* __restrict__ state, const int* __restrict__ gidx,
    float* __restrict__ gstate, int N)
{
    int n = blockIdx.x * blockDim.x + threadIdx.x;
    if (n >= N) return;
    int g = gidx[n];
    const float2* sp = (const float2*)(state + (size_t)n * SD);
    float* dst = gstate + (size_t)g * SD;
#pragma unroll
    for (int h = 0; h < 5; h++) {
        float2 v = sp[h];
        atomicAdd(dst + 2 * h, v.x);
        atomicAdd(dst + 2 * h + 1, v.y);
    }
}

// ============================ launch ============================

extern "C" void kernel_launch(void* const* d_in, const int* in_sizes, int n_in,
                              void* d_out, int out_size, void* d_ws, size_t ws_size,
                              hipStream_t stream) {
    const float* coords = (const float*)d_in[0];
    const float* elen   = (const float*)d_in[1];
    const float* evec   = (const float*)d_in[2];
    const float* Wm     = (const float*)d_in[3];
    const float* bm     = (const float*)d_in[4];
    const float* Wo     = (const float*)d_in[5];
    const float* bo     = (const float*)d_in[6];
    const int* nfrom    = (const int*)d_in[7];
    const int* nto      = (const int*)d_in[8];
    const int* gidx     = (const int*)d_in[9];

    const int E = in_sizes[1];
    const int N = in_sizes[9];
    const int G = out_size / 4;

    const int BLK = 256;
    const int eg = (E + BLK - 1) / BLK;
    const int ng = (N + BLK - 1) / BLK;
    const int gg = (G + BLK - 1) / BLK;

    auto align256 = [](size_t x) { return (x + 255) & ~(size_t)255; };
    const size_t state_bytes = align256((size_t)N * SD * sizeof(float));
    const size_t off_bytes   = align256((size_t)(N + 1) * sizeof(unsigned));
    const size_t cnt_bytes   = align256((size_t)N * sizeof(unsigned));
    const size_t bsum_bytes  = align256(4096);
    const size_t goff_bytes  = align256((size_t)(G + 1) * sizeof(unsigned));
    const size_t gst_bytes   = align256((size_t)G * SD * sizeof(float));
    const size_t nfs_bytes   = align256((size_t)E * sizeof(int));
    const size_t geo_bytes   = align256((size_t)E * 4 * sizeof(float));

    size_t o = 0;
    char* w = (char*)d_ws;
    float* stateA   = (float*)(w + o);    o += state_bytes;
    float* stateB   = (float*)(w + o);    o += state_bytes;
    unsigned* off   = (unsigned*)(w + o); o += off_bytes;
    unsigned* cur   = (unsigned*)(w + o); o += cnt_bytes;
    unsigned* cnt   = (unsigned*)(w + o); o += cnt_bytes;
    unsigned* bsum  = (unsigned*)(w + o); o += bsum_bytes;
    unsigned* goff  = (unsigned*)(w + o); o += goff_bytes;
    float* gstate   = (float*)(w + o);    o += gst_bytes;
    int* nfrom_s    = (int*)(w + o);      o += nfs_bytes;
    float4* geo_s   = (float4*)(w + o);   o += geo_bytes;

    const int nb = (N + 1023) / 1024;  // scan level-1 blocks (<=256 required)

    if (o <= ws_size && nb <= 256) {
        // ---- CSR gather path ----
        hipMemsetAsync(cnt, 0, (size_t)N * sizeof(unsigned), stream);
        hist_kernel<<<eg, BLK, 0, stream>>>(nto, cnt, E);
        scan1_kernel<<<nb, BLK, 0, stream>>>(cnt, off, bsum, N);
        scan2_kernel<<<1, BLK, 0, stream>>>(bsum, nb);
        scan3_kernel<<<ng, BLK, 0, stream>>>(off, cur, bsum, N, E);
        scatter_kernel<<<eg, BLK, 0, stream>>>(coords, elen, evec, nfrom, nto,
                                               cur, nfrom_s, geo_s, E);
        round_kernel<true><<<ng, BLK, 0, stream>>>(off, nfrom_s, geo_s, Wm, bm,
                                                   stateB /*unused*/, stateA, N);
        round_kernel<false><<<ng, BLK, 0, stream>>>(off, nfrom_s, geo_s, Wm, bm,
                                                    stateA, stateB, N);
        round_kernel<false><<<ng, BLK, 0, stream>>>(off, nfrom_s, geo_s, Wm, bm,
                                                    stateB, stateA, N);
        goff_kernel<<<ng, BLK, 0, stream>>>(gidx, goff, N, G);
        gsum_kernel<<<(G * SD + BLK - 1) / BLK, BLK, 0, stream>>>(stateA, goff, gstate, G);
        out_kernel<<<gg, BLK, 0, stream>>>(gstate, Wo, bo, (float*)d_out, G);
    } else {
        // ---- fallback: R0 atomic path ----
        float* gstateF = (float*)(w + 2 * state_bytes);
        hipMemsetAsync(stateA, 0, state_bytes, stream);
        hipMemsetAsync(gstateF, 0, (size_t)G * SD * sizeof(float), stream);
        edge_kernel_fb<true><<<eg, BLK, 0, stream>>>(coords, elen, evec, Wm, bm,
                                                     nfrom, nto, stateA, stateA, E);
        hipMemcpyAsync(stateB, stateA, state_bytes, hipMemcpyDeviceToDevice, stream);
        edge_kernel_fb<false><<<eg, BLK, 0, stream>>>(coords, elen, evec, Wm, bm,
                                                      nfrom, nto, stateA, stateB, E);
        hipMemcpyAsync(stateA, stateB, state_bytes, hipMemcpyDeviceToDevice, stream);
        edge_kernel_fb<false><<<eg, BLK, 0, stream>>>(coords, elen, evec, Wm, bm,
                                                      nfrom, nto, stateB, stateA, E);
        graph_reduce_fb<<<ng, BLK, 0, stream>>>(stateA, gidx, gstateF, N);
        out_kernel<<<gg, BLK, 0, stream>>>(gstateF, Wo, bo, (float*)d_out, G);
    }
}